// Round 4
// baseline (620.934 us; speedup 1.0000x reference)
//
#include <hip/hip_runtime.h>

#define M_DIM 4096
#define K_DIM 16384
#define N_DIM 256
#define SPLIT 16
#define BK 64
#define KSLICE (K_DIM / SPLIT)   // 1024
#define NITER (KSLICE / BK)      // 16

typedef __bf16 bf16x8 __attribute__((ext_vector_type(8)));
typedef __bf16 bf16x4 __attribute__((ext_vector_type(4)));
typedef float f32x4 __attribute__((ext_vector_type(4)));

// ---------------- W transpose + convert: Wt[n][k] = bf16(W[k][n]) ----------------
__global__ __launch_bounds__(256) void wt_kernel(const float* __restrict__ W,
                                                 __bf16* __restrict__ Wt) {
  __shared__ float tile[64][65];
  const int k0 = blockIdx.x * 64, n0 = blockIdx.y * 64;
  const int t = threadIdx.x;
#pragma unroll
  for (int r = 0; r < 4; ++r) {
    int idx4 = r * 256 + t;
    int kr = idx4 >> 4, c4 = idx4 & 15;
    f32x4 v = *(const f32x4*)(W + (size_t)(k0 + kr) * N_DIM + n0 + c4 * 4);
#pragma unroll
    for (int j = 0; j < 4; ++j) tile[kr][c4 * 4 + j] = v[j];
  }
  __syncthreads();
#pragma unroll
  for (int r = 0; r < 4; ++r) {
    int nr = (t >> 4) + r * 16, k4 = t & 15;
    bf16x4 o;
#pragma unroll
    for (int j = 0; j < 4; ++j) o[j] = (__bf16)tile[k4 * 4 + j][nr];
    *(bf16x4*)(Wt + (size_t)(n0 + nr) * K_DIM + k0 + k4 * 4) = o;
  }
}

// ---------------- init: out = bias + coeff * (bitflip(g)-g) * W[idx,:] ----------------
__global__ __launch_bounds__(256) void init_kernel(const float* __restrict__ x,
                                                   const float* __restrict__ W,
                                                   const float* __restrict__ bvec,
                                                   const float* __restrict__ coeffp,
                                                   const int* __restrict__ idx,
                                                   const int* __restrict__ bp,
                                                   float* __restrict__ out) {
  const int row = blockIdx.x;
  const int o = threadIdx.x;
  const int iv = idx[row];
  const float g = x[(size_t)row * K_DIM + iv];
  const int bits = __float_as_int(g) ^ (1 << bp[row]);
  const float upd = __int_as_float(bits) - g;  // exact fp32
  out[(size_t)row * N_DIM + o] = bvec[o] + coeffp[0] * upd * W[(size_t)iv * N_DIM + o];
}

// ---------------- Main MFMA GEMM, fp32 atomic epilogue ----------------
// BM=64, BN=256 (full O -> x fetched exactly once), BK=64, 256 thr = 4 waves.
// global->reg->LDS pipeline; LDS 45 KiB -> 3 blocks/CU; grid 64x16 = 1024 blocks.
__global__ __launch_bounds__(256, 3) void gemm_kernel(const float* __restrict__ x,
                                                      const __bf16* __restrict__ Wt,
                                                      float* __restrict__ target) {
  __shared__ __bf16 As[64 * 72];
  __shared__ __bf16 Bs[256 * 72];

  const int t = threadIdx.x;
  const int l = t & 63;
  const int w = t >> 6;
  const int la = l & 15, q = l >> 4;
  const int m0 = blockIdx.x * 64;
  const int kbase = blockIdx.y * KSLICE;

  const int arow = t >> 4, ac4 = t & 15;
  const int bn = t >> 3, bk8 = (t & 7) * 8;

  const float* ap = x + (size_t)(m0 + arow) * K_DIM + kbase + ac4 * 4;
  const __bf16* bp = Wt + (size_t)bn * K_DIM + kbase + bk8;

  f32x4 areg[4];
  bf16x8 breg[8];

#pragma unroll
  for (int r = 0; r < 4; ++r) areg[r] = *(const f32x4*)(ap + (size_t)r * 16 * K_DIM);
#pragma unroll
  for (int c = 0; c < 8; ++c) breg[c] = *(const bf16x8*)(bp + (size_t)c * 32 * K_DIM);

  f32x4 acc[4][4];
  const f32x4 zero = {0.f, 0.f, 0.f, 0.f};
#pragma unroll
  for (int i = 0; i < 4; ++i)
#pragma unroll
    for (int j = 0; j < 4; ++j) acc[i][j] = zero;

  for (int it = 0; it < NITER; ++it) {
    __syncthreads();  // previous MFMA phase done reading LDS
#pragma unroll
    for (int r = 0; r < 4; ++r) {
      bf16x4 o = {(__bf16)areg[r][0], (__bf16)areg[r][1],
                  (__bf16)areg[r][2], (__bf16)areg[r][3]};
      *(bf16x4*)(&As[(arow + r * 16) * 72 + ac4 * 4]) = o;
    }
#pragma unroll
    for (int c = 0; c < 8; ++c)
      *(bf16x8*)(&Bs[(bn + c * 32) * 72 + bk8]) = breg[c];
    __syncthreads();  // LDS ready

    if (it + 1 < NITER) {
      ap += BK;
      bp += BK;
#pragma unroll
      for (int r = 0; r < 4; ++r) areg[r] = *(const f32x4*)(ap + (size_t)r * 16 * K_DIM);
#pragma unroll
      for (int c = 0; c < 8; ++c) breg[c] = *(const bf16x8*)(bp + (size_t)c * 32 * K_DIM);
    }

#pragma unroll
    for (int ks = 0; ks < 2; ++ks) {
      const int kb = ks * 32 + q * 8;
      bf16x8 a[4], b[4];
#pragma unroll
      for (int i = 0; i < 4; ++i)
        a[i] = *(const bf16x8*)(&As[(i * 16 + la) * 72 + kb]);
#pragma unroll
      for (int j = 0; j < 4; ++j)
        b[j] = *(const bf16x8*)(&Bs[(w * 64 + j * 16 + la) * 72 + kb]);
#pragma unroll
      for (int i = 0; i < 4; ++i)
#pragma unroll
        for (int j = 0; j < 4; ++j)
          acc[i][j] = __builtin_amdgcn_mfma_f32_16x16x32_bf16(a[i], b[j], acc[i][j], 0, 0, 0);
    }
  }

  // ---- epilogue: fp32 hardware-atomic accumulate (C/D: col=lane&15, row=quad*4+reg) ----
#pragma unroll
  for (int i = 0; i < 4; ++i) {
    int r0 = m0 + i * 16 + q * 4;
#pragma unroll
    for (int j = 0; j < 4; ++j) {
      int c = w * 64 + j * 16 + la;
#pragma unroll
      for (int r = 0; r < 4; ++r)
        unsafeAtomicAdd(&target[(size_t)(r0 + r) * N_DIM + c], acc[i][j][r]);
    }
  }
}

extern "C" void kernel_launch(void* const* d_in, const int* in_sizes, int n_in,
                              void* d_out, int out_size, void* d_ws, size_t ws_size,
                              hipStream_t stream) {
  const float* x = (const float*)d_in[0];
  const float* W = (const float*)d_in[1];
  const float* b = (const float*)d_in[2];
  const float* coeff = (const float*)d_in[3];
  const int* idx = (const int*)d_in[4];
  const int* bp = (const int*)d_in[5];
  float* out = (float*)d_out;

  __bf16* Wt = (__bf16*)d_ws;  // 8 MiB
  // dead scratch target for calibration replicas (never read; poisoned garbage ok)
  float* scr = (float*)((char*)d_ws + (64u << 20));

  hipLaunchKernelGGL(wt_kernel, dim3(K_DIM / 64, N_DIM / 64), dim3(256), 0, stream, W, Wt);
  hipLaunchKernelGGL(init_kernel, dim3(M_DIM), dim3(256), 0, stream,
                     x, W, b, coeff, idx, bp, out);
  hipLaunchKernelGGL(gemm_kernel, dim3(M_DIM / 64, SPLIT), dim3(256), 0, stream, x, Wt, out);
  // --- calibration replicas: measure t_gemm = (dur_r4 - dur_r3_adj) / 2 ---
  hipLaunchKernelGGL(gemm_kernel, dim3(M_DIM / 64, SPLIT), dim3(256), 0, stream, x, Wt, scr);
  hipLaunchKernelGGL(gemm_kernel, dim3(M_DIM / 64, SPLIT), dim3(256), 0, stream, x, Wt, scr);
}